// Round 1
// baseline (222.708 us; speedup 1.0000x reference)
//
#include <hip/hip_runtime.h>

#define B 16
#define S 4096
#define D 256
#define U 256
#define R 8        // rows per block in score kernel
#define CHUNK 128  // rows per block in context kernel
#define NCH (S / CHUNK)

// K1: pq[b][u] = query[b,:] . W2[:,u] + b2[u]
__global__ void k1_pq(const float* __restrict__ q, const float* __restrict__ W2,
                      const float* __restrict__ b2, float* __restrict__ pq) {
    int b = blockIdx.x;
    int u = threadIdx.x;
    const float* qb = q + b * D;
    float acc = b2[u];
#pragma unroll 8
    for (int d = 0; d < D; ++d)
        acc = fmaf(qb[d], W2[d * U + u], acc);
    pq[b * U + u] = acc;
}

// K2: score[b][s] = tanh(values[b,s,:] @ W1 + b1 + pq[b]) . V + bV
// one block = R rows of one batch; 256 threads, thread u owns column u.
__global__ void k2_scores(const float* __restrict__ values, const float* __restrict__ W1,
                          const float* __restrict__ b1, const float* __restrict__ V,
                          const float* __restrict__ bV, const float* __restrict__ pq,
                          float* __restrict__ scores) {
    __shared__ float vrow[R][D];
    __shared__ float red[4][R];
    const int chunksPerB = S / R;
    int b = blockIdx.x / chunksPerB;
    int s0 = (blockIdx.x % chunksPerB) * R;
    int t = threadIdx.x;

    // stage R value rows into LDS (coalesced)
    const float* src = values + ((size_t)b * S + s0) * D;
    float* dst = &vrow[0][0];
#pragma unroll
    for (int i = 0; i < R; ++i) dst[t + i * 256] = src[t + i * 256];
    __syncthreads();

    int u = t;
    float base = b1[u] + pq[b * U + u];
    float acc[R];
#pragma unroll
    for (int r = 0; r < R; ++r) acc[r] = base;

    for (int d = 0; d < D; d += 4) {
        float w0 = W1[(d + 0) * U + u];
        float w1 = W1[(d + 1) * U + u];
        float w2 = W1[(d + 2) * U + u];
        float w3 = W1[(d + 3) * U + u];
#pragma unroll
        for (int r = 0; r < R; ++r) {
            float4 vv = *(const float4*)&vrow[r][d];  // LDS broadcast read
            acc[r] = fmaf(vv.x, w0, acc[r]);
            acc[r] = fmaf(vv.y, w1, acc[r]);
            acc[r] = fmaf(vv.z, w2, acc[r]);
            acc[r] = fmaf(vv.w, w3, acc[r]);
        }
    }

    float Vu = V[u];
    int lane = t & 63, wid = t >> 6;
#pragma unroll
    for (int r = 0; r < R; ++r) {
        float c = tanhf(acc[r]) * Vu;
#pragma unroll
        for (int off = 32; off; off >>= 1) c += __shfl_down(c, off, 64);
        if (lane == 0) red[wid][r] = c;
    }
    __syncthreads();
    if (t < R) {
        float s = red[0][t] + red[1][t] + red[2][t] + red[3][t] + bV[0];
        scores[b * S + s0 + t] = s;
    }
}

// K3: per-batch softmax stats: m[b] = max_s score, Z[b] = sum exp(score - m)
__global__ void k3_stats(const float* __restrict__ scores, float* __restrict__ mz) {
    __shared__ float red[16];
    int b = blockIdx.x, t = threadIdx.x;
    int lane = t & 63, wid = t >> 6;
    const float* sc = scores + b * S;

    float m = -1e30f;
    for (int i = t; i < S; i += 1024) m = fmaxf(m, sc[i]);
#pragma unroll
    for (int off = 32; off; off >>= 1) m = fmaxf(m, __shfl_down(m, off, 64));
    if (lane == 0) red[wid] = m;
    __syncthreads();
    if (t < 16) {
        float v = red[t];
#pragma unroll
        for (int off = 8; off; off >>= 1) v = fmaxf(v, __shfl_down(v, off, 16));
        if (t == 0) red[0] = v;
    }
    __syncthreads();
    m = red[0];
    __syncthreads();

    float z = 0.f;
    for (int i = t; i < S; i += 1024) z += expf(sc[i] - m);
#pragma unroll
    for (int off = 32; off; off >>= 1) z += __shfl_down(z, off, 64);
    if (lane == 0) red[wid] = z;
    __syncthreads();
    if (t == 0) {
        float v = 0.f;
#pragma unroll
        for (int w = 0; w < 16; ++w) v += red[w];
        mz[b] = m;
        mz[16 + b] = v;
    }
}

// K4: weights out + partial context over CHUNK rows
__global__ void k4_ctx(const float* __restrict__ values, const float* __restrict__ scores,
                       const float* __restrict__ mz, float* __restrict__ partials,
                       float* __restrict__ wout) {
    __shared__ float wch[CHUNK];
    int b = blockIdx.x / NCH;
    int c = blockIdx.x % NCH;
    int s0 = c * CHUNK;
    int t = threadIdx.x;

    float m = mz[b];
    float invZ = 1.0f / mz[16 + b];
    if (t < CHUNK) {
        float w = expf(scores[b * S + s0 + t] - m) * invZ;
        wch[t] = w;
        wout[b * S + s0 + t] = w;
    }
    __syncthreads();

    const float* vb = values + ((size_t)b * S + s0) * D + t;
    float acc = 0.f;
#pragma unroll 4
    for (int s = 0; s < CHUNK; ++s)
        acc = fmaf(wch[s], vb[(size_t)s * D], acc);
    partials[(b * NCH + c) * D + t] = acc;
}

// K5: reduce partials -> context
__global__ void k5_final(const float* __restrict__ partials, float* __restrict__ ctx) {
    int b = blockIdx.x, t = threadIdx.x;
    float acc = 0.f;
#pragma unroll
    for (int c = 0; c < NCH; ++c) acc += partials[(b * NCH + c) * D + t];
    ctx[b * D + t] = acc;
}

extern "C" void kernel_launch(void* const* d_in, const int* in_sizes, int n_in,
                              void* d_out, int out_size, void* d_ws, size_t ws_size,
                              hipStream_t stream) {
    const float* values = (const float*)d_in[0];
    const float* query  = (const float*)d_in[1];
    const float* W1     = (const float*)d_in[2];
    const float* b1     = (const float*)d_in[3];
    const float* W2     = (const float*)d_in[4];
    const float* b2     = (const float*)d_in[5];
    const float* V      = (const float*)d_in[6];
    const float* bV     = (const float*)d_in[7];

    float* out  = (float*)d_out;
    float* ctx  = out;          // [B, D]
    float* wout = out + B * D;  // [B, S, 1]

    float* ws       = (float*)d_ws;
    float* pq       = ws;               // B*U     = 4096
    float* scores   = pq + B * U;       // B*S     = 65536
    float* mz       = scores + B * S;   // 2*B     = 32
    float* partials = mz + 32;          // B*NCH*D = 131072

    k1_pq<<<B, U, 0, stream>>>(query, W2, b2, pq);
    k2_scores<<<B * S / R, 256, 0, stream>>>(values, W1, b1, V, bV, pq, scores);
    k3_stats<<<B, 1024, 0, stream>>>(scores, mz);
    k4_ctx<<<B * NCH, 256, 0, stream>>>(values, scores, mz, partials, wout);
    k5_final<<<B, D, 0, stream>>>(partials, ctx);
}

// Round 2
// 59.727 us; speedup vs baseline: 3.7288x; 3.7288x over previous
//
#include <hip/hip_runtime.h>
#include <hip/hip_bf16.h>

#define B 16
#define S 4096
#define D 256
#define U 256
#define ROWS 64    // rows per block in score kernel
#define CHUNK 128  // rows per block in context kernel
#define NCH (S / CHUNK)

typedef short short8 __attribute__((ext_vector_type(8)));
typedef float f32x4 __attribute__((ext_vector_type(4)));

__device__ __forceinline__ ushort f2bf(float f) {
    union { float f; uint u; } x{f};
    uint r = (x.u + 0x7fffu + ((x.u >> 16) & 1u)) >> 16;  // RNE
    return (ushort)r;
}

__device__ __forceinline__ float fast_tanh(float x) {
    float e = __expf(2.0f * x);
    return 1.0f - 2.0f * __builtin_amdgcn_rcpf(e + 1.0f);
}

// K0: pack W1 (fp32 [D][U]) into bf16 MFMA B-fragment order:
// W1p[((nt*8 + kk)*64 + lane)*8 + e] = bf16(W1[kk*32 + (lane>>4)*8 + e][nt*16 + (lane&15)])
__global__ void k0_pack(const float* __restrict__ W1, ushort* __restrict__ W1p) {
    int nt = blockIdx.x, kk = blockIdx.y;
    int l = threadIdx.x;
    int colu = nt * 16 + (l & 15);
    int k0 = kk * 32 + (l >> 4) * 8;
    ushort* dst = W1p + (((nt * 8) + kk) * 64 + l) * 8;
#pragma unroll
    for (int e = 0; e < 8; ++e) dst[e] = f2bf(W1[(k0 + e) * U + colu]);
}

// K1: pqb[b][u] = query[b,:] . W2[:,u] + b2[u] + b1[u]
__global__ void k1_pq(const float* __restrict__ q, const float* __restrict__ W2,
                      const float* __restrict__ b2, const float* __restrict__ b1,
                      float* __restrict__ pqb) {
    int b = blockIdx.x;
    int u = threadIdx.x;
    const float* qb = q + b * D;
    float acc = b2[u] + b1[u];
#pragma unroll 8
    for (int d = 0; d < D; ++d)
        acc = fmaf(qb[d], W2[d * U + u], acc);
    pqb[b * U + u] = acc;
}

// K2: score[b][s] = tanh(values[b,s,:] @ W1 + pqb[b]) . V + bV   via bf16 MFMA
// block = 64 rows of one batch, 256 threads (4 waves); wave w owns cols [64w, 64w+64)
__global__ void k2_mfma(const float* __restrict__ values, const ushort* __restrict__ W1p,
                        const float* __restrict__ pqb, const float* __restrict__ V,
                        const float* __restrict__ bV, float* __restrict__ scores) {
    __shared__ ushort Alds[ROWS * 256];  // 64 rows x 256 bf16, XOR-swizzled
    __shared__ float red[4][ROWS];
    int b = blockIdx.x >> 6;             // S/ROWS = 64 chunks per batch
    int s0 = (blockIdx.x & 63) * ROWS;
    int t = threadIdx.x;
    int w = t >> 6, l = t & 63;
    char* lds = (char*)Alds;

    // stage 64x256 fp32 -> bf16 LDS, swizzled byte ^= (row&7)<<4
    const float* src = values + ((size_t)(b * S + s0)) * D;
#pragma unroll
    for (int i = 0; i < 16; ++i) {
        int row = i * 4 + w;
        int col = l * 4;
        float4 v = *(const float4*)&src[row * 256 + col];
        ushort4 h;
        h.x = f2bf(v.x); h.y = f2bf(v.y); h.z = f2bf(v.z); h.w = f2bf(v.w);
        int byte = (row * 512 + col * 2) ^ ((row & 7) << 4);
        *(ushort4*)(lds + byte) = h;
    }
    __syncthreads();

    int lrow = l & 15, lk = l >> 4;
    f32x4 acc[4][4];
#pragma unroll
    for (int mt = 0; mt < 4; ++mt)
#pragma unroll
        for (int nt = 0; nt < 4; ++nt) acc[mt][nt] = (f32x4){0.f, 0.f, 0.f, 0.f};

    for (int kk = 0; kk < 8; ++kk) {
        short8 afr[4], bfr[4];
#pragma unroll
        for (int mt = 0; mt < 4; ++mt) {
            int row = mt * 16 + lrow;
            int byte = (row * 512 + kk * 64 + lk * 16) ^ ((row & 7) << 4);
            afr[mt] = *(const short8*)(lds + byte);
        }
#pragma unroll
        for (int nt = 0; nt < 4; ++nt) {
            int ntile = w * 4 + nt;
            bfr[nt] = *(const short8*)&W1p[(((ntile * 8) + kk) * 64 + l) * 8];
        }
#pragma unroll
        for (int mt = 0; mt < 4; ++mt)
#pragma unroll
            for (int nt = 0; nt < 4; ++nt)
                acc[mt][nt] = __builtin_amdgcn_mfma_f32_16x16x32_bf16(
                    afr[mt], bfr[nt], acc[mt][nt], 0, 0, 0);
    }

    // epilogue: tanh, .V, reduce over u
    float bb[4], vv[4];
#pragma unroll
    for (int nt = 0; nt < 4; ++nt) {
        int u = (w * 4 + nt) * 16 + lrow;
        bb[nt] = pqb[b * U + u];
        vv[nt] = V[u];
    }
#pragma unroll
    for (int mt = 0; mt < 4; ++mt) {
#pragma unroll
        for (int r = 0; r < 4; ++r) {
            float s = 0.f;
#pragma unroll
            for (int nt = 0; nt < 4; ++nt)
                s += fast_tanh(acc[mt][nt][r] + bb[nt]) * vv[nt];
            // reduce across the 16 lanes holding the same row (low 4 lane bits)
            s += __shfl_xor(s, 1);
            s += __shfl_xor(s, 2);
            s += __shfl_xor(s, 4);
            s += __shfl_xor(s, 8);
            if (lrow == 0) red[w][mt * 16 + lk * 4 + r] = s;
        }
    }
    __syncthreads();
    if (t < ROWS)
        scores[b * S + s0 + t] =
            red[0][t] + red[1][t] + red[2][t] + red[3][t] + bV[0];
}

// K3: per-batch softmax stats: m[b] = max_s score, Z[b] = sum exp(score - m)
__global__ void k3_stats(const float* __restrict__ scores, float* __restrict__ mz) {
    __shared__ float red[16];
    int b = blockIdx.x, t = threadIdx.x;
    int lane = t & 63, wid = t >> 6;
    const float* sc = scores + b * S;

    float m = -1e30f;
    for (int i = t; i < S; i += 1024) m = fmaxf(m, sc[i]);
#pragma unroll
    for (int off = 32; off; off >>= 1) m = fmaxf(m, __shfl_down(m, off, 64));
    if (lane == 0) red[wid] = m;
    __syncthreads();
    if (t < 16) {
        float v = red[t];
#pragma unroll
        for (int off = 8; off; off >>= 1) v = fmaxf(v, __shfl_down(v, off, 16));
        if (t == 0) red[0] = v;
    }
    __syncthreads();
    m = red[0];
    __syncthreads();

    float z = 0.f;
    for (int i = t; i < S; i += 1024) z += __expf(sc[i] - m);
#pragma unroll
    for (int off = 32; off; off >>= 1) z += __shfl_down(z, off, 64);
    if (lane == 0) red[wid] = z;
    __syncthreads();
    if (t == 0) {
        float v = 0.f;
#pragma unroll
        for (int w = 0; w < 16; ++w) v += red[w];
        mz[b] = m;
        mz[16 + b] = v;
    }
}

// K4: weights out + partial context over CHUNK rows
__global__ void k4_ctx(const float* __restrict__ values, const float* __restrict__ scores,
                       const float* __restrict__ mz, float* __restrict__ partials,
                       float* __restrict__ wout) {
    __shared__ float wch[CHUNK];
    int b = blockIdx.x / NCH;
    int c = blockIdx.x % NCH;
    int s0 = c * CHUNK;
    int t = threadIdx.x;

    float m = mz[b];
    float invZ = 1.0f / mz[16 + b];
    if (t < CHUNK) {
        float w = __expf(scores[b * S + s0 + t] - m) * invZ;
        wch[t] = w;
        wout[b * S + s0 + t] = w;
    }
    __syncthreads();

    const float* vb = values + ((size_t)b * S + s0) * D + t;
    float acc = 0.f;
#pragma unroll 4
    for (int s = 0; s < CHUNK; ++s)
        acc = fmaf(wch[s], vb[(size_t)s * D], acc);
    partials[(b * NCH + c) * D + t] = acc;
}

// K5: reduce partials -> context
__global__ void k5_final(const float* __restrict__ partials, float* __restrict__ ctx) {
    int b = blockIdx.x, t = threadIdx.x;
    float acc = 0.f;
#pragma unroll
    for (int c = 0; c < NCH; ++c) acc += partials[(b * NCH + c) * D + t];
    ctx[b * D + t] = acc;
}

extern "C" void kernel_launch(void* const* d_in, const int* in_sizes, int n_in,
                              void* d_out, int out_size, void* d_ws, size_t ws_size,
                              hipStream_t stream) {
    const float* values = (const float*)d_in[0];
    const float* query  = (const float*)d_in[1];
    const float* W1     = (const float*)d_in[2];
    const float* b1     = (const float*)d_in[3];
    const float* W2     = (const float*)d_in[4];
    const float* b2     = (const float*)d_in[5];
    const float* V      = (const float*)d_in[6];
    const float* bV     = (const float*)d_in[7];

    float* out  = (float*)d_out;
    float* ctx  = out;          // [B, D]
    float* wout = out + B * D;  // [B, S, 1]

    float* ws       = (float*)d_ws;
    float* pqb      = ws;               // B*U      = 4096
    float* scores   = pqb + B * U;      // B*S      = 65536
    float* mz       = scores + B * S;   // 2*B      = 32
    float* partials = mz + 32;          // B*NCH*D  = 131072
    ushort* W1p     = (ushort*)(partials + B * NCH * D);  // 65536 ushorts

    k0_pack<<<dim3(16, 8), 64, 0, stream>>>(W1, W1p);
    k1_pq<<<B, U, 0, stream>>>(query, W2, b2, b1, pqb);
    k2_mfma<<<B * (S / ROWS), 256, 0, stream>>>(values, W1p, pqb, V, bV, scores);
    k3_stats<<<B, 1024, 0, stream>>>(scores, mz);
    k4_ctx<<<B * NCH, 256, 0, stream>>>(values, scores, mz, partials, wout);
    k5_final<<<B, D, 0, stream>>>(partials, ctx);
}

// Round 3
// 49.663 us; speedup vs baseline: 4.4844x; 1.2027x over previous
//
#include <hip/hip_runtime.h>
#include <hip/hip_bf16.h>

#define B 16
#define S 4096
#define D 256
#define U 256
#define ROWS 64    // rows per block in score kernel
#define CHUNK 128  // rows per block in context kernel
#define NCH (S / CHUNK)

typedef short short8 __attribute__((ext_vector_type(8)));
typedef float f32x4 __attribute__((ext_vector_type(4)));

__device__ __forceinline__ ushort f2bf(float f) {
    union { float f; uint u; } x{f};
    uint r = (x.u + 0x7fffu + ((x.u >> 16) & 1u)) >> 16;  // RNE
    return (ushort)r;
}

__device__ __forceinline__ float fast_tanh(float x) {
    float e = __expf(2.0f * x);
    return 1.0f - 2.0f * __builtin_amdgcn_rcpf(e + 1.0f);
}

// KA: fused setup.
//  blocks 0..15 : pqb[b][u] = query[b,:].W2[:,u] + b2[u] + b1[u]
//  blocks 16..23: pack W1 (fp32 [D][U]) into bf16 MFMA B-fragment order, one kk each
//  blocks 24..31: zero ctx (atomicAdd target)
__global__ void ka_setup(const float* __restrict__ q, const float* __restrict__ W2,
                         const float* __restrict__ b2, const float* __restrict__ b1,
                         const float* __restrict__ W1, float* __restrict__ pqb,
                         ushort* __restrict__ W1p, float* __restrict__ ctx) {
    int bid = blockIdx.x, t = threadIdx.x;
    if (bid < 16) {
        int b = bid, u = t;
        const float* qb = q + b * D;
        float acc = b2[u] + b1[u];
#pragma unroll 8
        for (int d = 0; d < D; ++d)
            acc = fmaf(qb[d], W2[d * U + u], acc);
        pqb[b * U + u] = acc;
    } else if (bid < 24) {
        int kk = bid - 16;
        int l = t & 63, g = t >> 6;
        int colu0 = l & 15;
        int k0 = kk * 32 + (l >> 4) * 8;
#pragma unroll
        for (int i = 0; i < 4; ++i) {
            int nt = g * 4 + i;
            int colu = nt * 16 + colu0;
            ushort* dst = W1p + (((nt * 8) + kk) * 64 + l) * 8;
#pragma unroll
            for (int e = 0; e < 8; ++e) dst[e] = f2bf(W1[(k0 + e) * U + colu]);
        }
    } else {
        int i = (bid - 24) * 256 + t;
        ctx[i] = 0.f;
        ctx[i + 2048] = 0.f;
    }
}

// KB: score[b][s] = tanh(values[b,s,:] @ W1 + pqb[b]) . V + bV   via bf16 MFMA,
// plus per-64-row-chunk softmax stats (m_c, z_c).
// block = 64 rows of one batch, 256 threads (4 waves); wave w owns cols [64w, 64w+64)
__global__ void kb_scores(const float* __restrict__ values, const ushort* __restrict__ W1p,
                          const float* __restrict__ pqb, const float* __restrict__ V,
                          const float* __restrict__ bV, float* __restrict__ scores,
                          float* __restrict__ cstats) {
    __shared__ ushort Alds[ROWS * 256];  // 64 rows x 256 bf16, XOR-swizzled
    __shared__ float red[4][ROWS];
    int b = blockIdx.x >> 6;             // S/ROWS = 64 chunks per batch
    int s0 = (blockIdx.x & 63) * ROWS;
    int t = threadIdx.x;
    int w = t >> 6, l = t & 63;
    char* lds = (char*)Alds;

    // stage 64x256 fp32 -> bf16 LDS, swizzled byte ^= (row&7)<<4
    const float* src = values + ((size_t)(b * S + s0)) * D;
#pragma unroll
    for (int i = 0; i < 16; ++i) {
        int row = i * 4 + w;
        int col = l * 4;
        float4 v = *(const float4*)&src[row * 256 + col];
        ushort4 h;
        h.x = f2bf(v.x); h.y = f2bf(v.y); h.z = f2bf(v.z); h.w = f2bf(v.w);
        int byte = (row * 512 + col * 2) ^ ((row & 7) << 4);
        *(ushort4*)(lds + byte) = h;
    }
    __syncthreads();

    int lrow = l & 15, lk = l >> 4;
    f32x4 acc[4][4];
#pragma unroll
    for (int mt = 0; mt < 4; ++mt)
#pragma unroll
        for (int nt = 0; nt < 4; ++nt) acc[mt][nt] = (f32x4){0.f, 0.f, 0.f, 0.f};

    for (int kk = 0; kk < 8; ++kk) {
        short8 afr[4], bfr[4];
#pragma unroll
        for (int mt = 0; mt < 4; ++mt) {
            int row = mt * 16 + lrow;
            int byte = (row * 512 + kk * 64 + lk * 16) ^ ((row & 7) << 4);
            afr[mt] = *(const short8*)(lds + byte);
        }
#pragma unroll
        for (int nt = 0; nt < 4; ++nt) {
            int ntile = w * 4 + nt;
            bfr[nt] = *(const short8*)&W1p[(((ntile * 8) + kk) * 64 + l) * 8];
        }
#pragma unroll
        for (int mt = 0; mt < 4; ++mt)
#pragma unroll
            for (int nt = 0; nt < 4; ++nt)
                acc[mt][nt] = __builtin_amdgcn_mfma_f32_16x16x32_bf16(
                    afr[mt], bfr[nt], acc[mt][nt], 0, 0, 0);
    }

    // epilogue: tanh, .V, reduce over u
    float bb[4], vv[4];
#pragma unroll
    for (int nt = 0; nt < 4; ++nt) {
        int u = (w * 4 + nt) * 16 + lrow;
        bb[nt] = pqb[b * U + u];
        vv[nt] = V[u];
    }
#pragma unroll
    for (int mt = 0; mt < 4; ++mt) {
#pragma unroll
        for (int r = 0; r < 4; ++r) {
            float s = 0.f;
#pragma unroll
            for (int nt = 0; nt < 4; ++nt)
                s += fast_tanh(acc[mt][nt][r] + bb[nt]) * vv[nt];
            // reduce across the 16 lanes holding the same row (low 4 lane bits)
            s += __shfl_xor(s, 1);
            s += __shfl_xor(s, 2);
            s += __shfl_xor(s, 4);
            s += __shfl_xor(s, 8);
            if (lrow == 0) red[w][mt * 16 + lk * 4 + r] = s;
        }
    }
    __syncthreads();
    if (t < ROWS) {  // t<64 == all of wave 0
        float s = red[0][t] + red[1][t] + red[2][t] + red[3][t] + bV[0];
        scores[b * S + s0 + t] = s;
        // per-chunk softmax stats across the 64 lanes
        float m = s;
#pragma unroll
        for (int off = 32; off; off >>= 1) m = fmaxf(m, __shfl_xor(m, off));
        float z = __expf(s - m);
#pragma unroll
        for (int off = 32; off; off >>= 1) z += __shfl_xor(z, off);
        if (t == 0) {
            cstats[2 * blockIdx.x] = m;
            cstats[2 * blockIdx.x + 1] = z;
        }
    }
}

// KC: per 128-row chunk: reduce batch stats, weights out, partial context, atomicAdd.
__global__ void kc_ctx(const float* __restrict__ values, const float* __restrict__ scores,
                       const float* __restrict__ cstats, float* __restrict__ wout,
                       float* __restrict__ ctx) {
    __shared__ float wch[CHUNK];
    __shared__ float stats[2];
    __shared__ float part[4][D];
    int b = blockIdx.x / NCH;
    int c = blockIdx.x % NCH;
    int s0 = c * CHUNK;
    int t = threadIdx.x;

    if (t < 64) {  // wave 0: reduce this batch's 64 chunk stats
        float m = cstats[2 * (b * 64 + t)];
        float z = cstats[2 * (b * 64 + t) + 1];
        float M = m;
#pragma unroll
        for (int off = 32; off; off >>= 1) M = fmaxf(M, __shfl_xor(M, off));
        float zz = z * __expf(m - M);
#pragma unroll
        for (int off = 32; off; off >>= 1) zz += __shfl_xor(zz, off);
        if (t == 0) { stats[0] = M; stats[1] = zz; }
    }
    __syncthreads();
    float M = stats[0];
    float invZ = 1.0f / stats[1];

    if (t < CHUNK) {
        float w = __expf(scores[b * S + s0 + t] - M) * invZ;
        wch[t] = w;
        wout[b * S + s0 + t] = w;
    }
    __syncthreads();

    // partial context: 4 s-groups x 64 lanes x float4 cols
    int sg = t >> 6, c4 = (t & 63) * 4;
    const float* vb = values + ((size_t)(b * S + s0 + sg * 32)) * D + c4;
    float4 acc = {0.f, 0.f, 0.f, 0.f};
#pragma unroll 4
    for (int s = 0; s < 32; ++s) {
        float4 v = *(const float4*)&vb[(size_t)s * D];
        float w = wch[sg * 32 + s];
        acc.x = fmaf(w, v.x, acc.x);
        acc.y = fmaf(w, v.y, acc.y);
        acc.z = fmaf(w, v.z, acc.z);
        acc.w = fmaf(w, v.w, acc.w);
    }
    *(float4*)&part[sg][c4] = acc;
    __syncthreads();

    float sum = part[0][t] + part[1][t] + part[2][t] + part[3][t];
    atomicAdd(&ctx[b * D + t], sum);
}

extern "C" void kernel_launch(void* const* d_in, const int* in_sizes, int n_in,
                              void* d_out, int out_size, void* d_ws, size_t ws_size,
                              hipStream_t stream) {
    const float* values = (const float*)d_in[0];
    const float* query  = (const float*)d_in[1];
    const float* W1     = (const float*)d_in[2];
    const float* b1     = (const float*)d_in[3];
    const float* W2     = (const float*)d_in[4];
    const float* b2     = (const float*)d_in[5];
    const float* V      = (const float*)d_in[6];
    const float* bV     = (const float*)d_in[7];

    float* out  = (float*)d_out;
    float* ctx  = out;          // [B, D]
    float* wout = out + B * D;  // [B, S, 1]

    float* ws     = (float*)d_ws;
    float* pqb    = ws;                 // B*U        = 4096
    float* scores = pqb + B * U;        // B*S        = 65536
    float* cstats = scores + B * S;     // 2*B*64     = 2048
    ushort* W1p   = (ushort*)(cstats + 2048);  // 65536 ushorts

    ka_setup<<<32, 256, 0, stream>>>(query, W2, b2, b1, W1, pqb, W1p, ctx);
    kb_scores<<<B * (S / ROWS), 256, 0, stream>>>(values, W1p, pqb, V, bV, scores, cstats);
    kc_ctx<<<B * NCH, 256, 0, stream>>>(values, scores, cstats, wout, ctx);
}

// Round 4
// 46.753 us; speedup vs baseline: 4.7635x; 1.0622x over previous
//
#include <hip/hip_runtime.h>
#include <hip/hip_bf16.h>

#define B 16
#define S 4096
#define D 256
#define U 256
#define ROWS 64    // rows per block in score kernel
#define NCHK (S / ROWS)  // 64 chunks per batch

typedef short short8 __attribute__((ext_vector_type(8)));
typedef float f32x4 __attribute__((ext_vector_type(4)));

__device__ __forceinline__ ushort f2bf(float f) {
    union { float f; uint u; } x{f};
    uint r = (x.u + 0x7fffu + ((x.u >> 16) & 1u)) >> 16;  // RNE
    return (ushort)r;
}

__device__ __forceinline__ float fast_tanh(float x) {
    float e = __expf(2.0f * x);
    return 1.0f - 2.0f * __builtin_amdgcn_rcpf(e + 1.0f);
}

// KA: fused setup.
//  blocks 0..15 : pqb[b][u] = query[b,:].W2[:,u] + b2[u] + b1[u]
//  blocks 16..23: pack W1 (fp32 [D][U]) into bf16 MFMA B-fragment order, one kk each
__global__ void ka_setup(const float* __restrict__ q, const float* __restrict__ W2,
                         const float* __restrict__ b2, const float* __restrict__ b1,
                         const float* __restrict__ W1, float* __restrict__ pqb,
                         ushort* __restrict__ W1p) {
    int bid = blockIdx.x, t = threadIdx.x;
    if (bid < 16) {
        int b = bid, u = t;
        const float* qb = q + b * D;
        float acc = b2[u] + b1[u];
#pragma unroll 8
        for (int d = 0; d < D; ++d)
            acc = fmaf(qb[d], W2[d * U + u], acc);
        pqb[b * U + u] = acc;
    } else {
        int kk = bid - 16;
        int l = t & 63, g = t >> 6;
        int colu0 = l & 15;
        int k0 = kk * 32 + (l >> 4) * 8;
#pragma unroll
        for (int i = 0; i < 4; ++i) {
            int nt = g * 4 + i;
            int colu = nt * 16 + colu0;
            ushort* dst = W1p + (((nt * 8) + kk) * 64 + l) * 8;
#pragma unroll
            for (int e = 0; e < 8; ++e) dst[e] = f2bf(W1[(k0 + e) * U + colu]);
        }
    }
}

// KB: per 64-row chunk: scores via bf16 MFMA, chunk softmax stats (m_c, z_c),
// and unnormalized partial context cpart[chunk][d] = sum_row e^{s-m_c} * values[row][d].
// block = 64 rows of one batch, 256 threads (4 waves); wave w owns cols [64w, 64w+64)
__global__ void kb_scores(const float* __restrict__ values, const ushort* __restrict__ W1p,
                          const float* __restrict__ pqb, const float* __restrict__ V,
                          const float* __restrict__ bV, float* __restrict__ scores,
                          float* __restrict__ cstats, float* __restrict__ cpart) {
    __shared__ ushort Alds[ROWS * 256];  // 64 rows x 256 bf16, XOR-swizzled
    __shared__ float red[4][ROWS];
    __shared__ float wch[ROWS];
    int b = blockIdx.x >> 6;
    int s0 = (blockIdx.x & 63) * ROWS;
    int t = threadIdx.x;
    int w = t >> 6, l = t & 63;
    char* lds = (char*)Alds;

    // stage 64x256 fp32 -> bf16 LDS, swizzled byte ^= (row&7)<<4
    const float* src = values + ((size_t)(b * S + s0)) * D;
#pragma unroll
    for (int i = 0; i < 16; ++i) {
        int row = i * 4 + w;
        int col = l * 4;
        float4 v = *(const float4*)&src[row * 256 + col];
        ushort4 h;
        h.x = f2bf(v.x); h.y = f2bf(v.y); h.z = f2bf(v.z); h.w = f2bf(v.w);
        int byte = (row * 512 + col * 2) ^ ((row & 7) << 4);
        *(ushort4*)(lds + byte) = h;
    }
    __syncthreads();

    int lrow = l & 15, lk = l >> 4;
    f32x4 acc[4][4];
#pragma unroll
    for (int mt = 0; mt < 4; ++mt)
#pragma unroll
        for (int nt = 0; nt < 4; ++nt) acc[mt][nt] = (f32x4){0.f, 0.f, 0.f, 0.f};

    for (int kk = 0; kk < 8; ++kk) {
        short8 afr[4], bfr[4];
#pragma unroll
        for (int mt = 0; mt < 4; ++mt) {
            int row = mt * 16 + lrow;
            int byte = (row * 512 + kk * 64 + lk * 16) ^ ((row & 7) << 4);
            afr[mt] = *(const short8*)(lds + byte);
        }
#pragma unroll
        for (int nt = 0; nt < 4; ++nt) {
            int ntile = w * 4 + nt;
            bfr[nt] = *(const short8*)&W1p[(((ntile * 8) + kk) * 64 + l) * 8];
        }
#pragma unroll
        for (int mt = 0; mt < 4; ++mt)
#pragma unroll
            for (int nt = 0; nt < 4; ++nt)
                acc[mt][nt] = __builtin_amdgcn_mfma_f32_16x16x32_bf16(
                    afr[mt], bfr[nt], acc[mt][nt], 0, 0, 0);
    }

    // epilogue: tanh, .V, reduce over u
    float bb[4], vv[4];
#pragma unroll
    for (int nt = 0; nt < 4; ++nt) {
        int u = (w * 4 + nt) * 16 + lrow;
        bb[nt] = pqb[b * U + u];
        vv[nt] = V[u];
    }
#pragma unroll
    for (int mt = 0; mt < 4; ++mt) {
#pragma unroll
        for (int r = 0; r < 4; ++r) {
            float s = 0.f;
#pragma unroll
            for (int nt = 0; nt < 4; ++nt)
                s += fast_tanh(acc[mt][nt][r] + bb[nt]) * vv[nt];
            s += __shfl_xor(s, 1);
            s += __shfl_xor(s, 2);
            s += __shfl_xor(s, 4);
            s += __shfl_xor(s, 8);
            if (lrow == 0) red[w][mt * 16 + lk * 4 + r] = s;
        }
    }
    __syncthreads();
    if (t < ROWS) {  // wave 0
        float s = red[0][t] + red[1][t] + red[2][t] + red[3][t] + bV[0];
        scores[b * S + s0 + t] = s;
        float m = s;
#pragma unroll
        for (int off = 32; off; off >>= 1) m = fmaxf(m, __shfl_xor(m, off));
        float z0 = __expf(s - m);
        wch[t] = z0;
        float z = z0;
#pragma unroll
        for (int off = 32; off; off >>= 1) z += __shfl_xor(z, off);
        if (t == 0) {
            cstats[2 * blockIdx.x] = m;
            cstats[2 * blockIdx.x + 1] = z;
        }
    }
    __syncthreads();

    // partial context: thread t owns column t, fp32 values from L2-hot global
    const float* vsrc = values + ((size_t)(b * S + s0)) * D + t;
    float cacc = 0.f;
#pragma unroll 8
    for (int r = 0; r < ROWS; ++r)
        cacc = fmaf(wch[r], vsrc[(size_t)r * D], cacc);
    cpart[(size_t)blockIdx.x * D + t] = cacc;
}

// KC: finisher. 4 blocks per batch (q = quarter).
//  - reduce 64 chunk stats -> M, Z (redundant per block)
//  - ctx[b][q*64 + dl] = sum_c e^{m_c-M} cpart[c][d] / Z
//  - wout[b][q*1024 .. +1024) = e^{score-M}/Z
__global__ void kc_final(const float* __restrict__ scores, const float* __restrict__ cstats,
                         const float* __restrict__ cpart, float* __restrict__ wout,
                         float* __restrict__ ctx) {
    __shared__ float scl[NCHK];
    __shared__ float stats[2];
    __shared__ float part[4][64];
    int b = blockIdx.x >> 2, q = blockIdx.x & 3;
    int t = threadIdx.x;

    if (t < 64) {
        float m = cstats[2 * (b * NCHK + t)];
        float z = cstats[2 * (b * NCHK + t) + 1];
        float M = m;
#pragma unroll
        for (int off = 32; off; off >>= 1) M = fmaxf(M, __shfl_xor(M, off));
        float zz = z * __expf(m - M);
#pragma unroll
        for (int off = 32; off; off >>= 1) zz += __shfl_xor(zz, off);
        scl[t] = __expf(m - M);
        if (t == 0) { stats[0] = M; stats[1] = zz; }
    }
    __syncthreads();
    float M = stats[0];
    float invZ = 1.0f / stats[1];

    int tq = t >> 6, dl = t & 63;
    int d = q * 64 + dl;
    float acc = 0.f;
#pragma unroll
    for (int i = 0; i < 16; ++i) {
        int c = tq * 16 + i;
        acc = fmaf(scl[c], cpart[(size_t)(b * NCHK + c) * D + d], acc);
    }
    part[tq][dl] = acc;

#pragma unroll
    for (int i = 0; i < 4; ++i) {
        int s = q * 1024 + i * 256 + t;
        wout[b * S + s] = __expf(scores[b * S + s] - M) * invZ;
    }
    __syncthreads();
    if (t < 64)
        ctx[b * D + q * 64 + t] =
            (part[0][t] + part[1][t] + part[2][t] + part[3][t]) * invZ;
}

extern "C" void kernel_launch(void* const* d_in, const int* in_sizes, int n_in,
                              void* d_out, int out_size, void* d_ws, size_t ws_size,
                              hipStream_t stream) {
    const float* values = (const float*)d_in[0];
    const float* query  = (const float*)d_in[1];
    const float* W1     = (const float*)d_in[2];
    const float* b1     = (const float*)d_in[3];
    const float* W2     = (const float*)d_in[4];
    const float* b2     = (const float*)d_in[5];
    const float* V      = (const float*)d_in[6];
    const float* bV     = (const float*)d_in[7];

    float* out  = (float*)d_out;
    float* ctx  = out;          // [B, D]
    float* wout = out + B * D;  // [B, S, 1]

    float* ws     = (float*)d_ws;
    float* pqb    = ws;                 // B*U          = 4096
    float* scores = pqb + B * U;        // B*S          = 65536
    float* cstats = scores + B * S;     // 2*B*NCHK     = 2048
    float* cpart  = cstats + 2048;      // B*NCHK*D     = 262144
    ushort* W1p   = (ushort*)(cpart + B * NCHK * D);  // 65536 ushorts

    ka_setup<<<24, 256, 0, stream>>>(query, W2, b2, b1, W1, pqb, W1p);
    kb_scores<<<B * NCHK, 256, 0, stream>>>(values, W1p, pqb, V, bV, scores, cstats, cpart);
    kc_final<<<B * 4, 256, 0, stream>>>(scores, cstats, cpart, wout, ctx);
}

// Round 5
// 42.682 us; speedup vs baseline: 5.2178x; 1.0954x over previous
//
#include <hip/hip_runtime.h>
#include <hip/hip_bf16.h>

#define B 16
#define S 4096
#define D 256
#define U 256
#define ROWS 64    // rows per block in score kernel
#define NCHK (S / ROWS)  // 64 chunks per batch

typedef short short8 __attribute__((ext_vector_type(8)));
typedef float f32x4 __attribute__((ext_vector_type(4)));

__device__ __forceinline__ ushort f2bf(float f) {
    union { float f; uint u; } x{f};
    uint r = (x.u + 0x7fffu + ((x.u >> 16) & 1u)) >> 16;  // RNE
    return (ushort)r;
}

__device__ __forceinline__ float bf2f(ushort u) {
    union { uint i; float f; } cv;
    cv.i = (uint)u << 16;
    return cv.f;
}

__device__ __forceinline__ float fast_tanh(float x) {
    float e = __expf(2.0f * x);
    return 1.0f - 2.0f * __builtin_amdgcn_rcpf(e + 1.0f);
}

// KA: fused setup.
//  blocks 0..15 : pqb[b][u] = query[b,:].W2[:,u] + b2[u] + b1[u]
//  blocks 16..23: pack W1 (fp32 [D][U]) into bf16 MFMA B-fragment order, one kk each
__global__ void ka_setup(const float* __restrict__ q, const float* __restrict__ W2,
                         const float* __restrict__ b2, const float* __restrict__ b1,
                         const float* __restrict__ W1, float* __restrict__ pqb,
                         ushort* __restrict__ W1p) {
    int bid = blockIdx.x, t = threadIdx.x;
    if (bid < 16) {
        int b = bid, u = t;
        const float* qb = q + b * D;
        float acc = b2[u] + b1[u];
#pragma unroll 8
        for (int d = 0; d < D; ++d)
            acc = fmaf(qb[d], W2[d * U + u], acc);
        pqb[b * U + u] = acc;
    } else {
        int kk = bid - 16;
        int l = t & 63, g = t >> 6;
        int colu0 = l & 15;
        int k0 = kk * 32 + (l >> 4) * 8;
#pragma unroll
        for (int i = 0; i < 4; ++i) {
            int nt = g * 4 + i;
            int colu = nt * 16 + colu0;
            ushort* dst = W1p + (((nt * 8) + kk) * 64 + l) * 8;
#pragma unroll
            for (int e = 0; e < 8; ++e) dst[e] = f2bf(W1[(k0 + e) * U + colu]);
        }
    }
}

// KB: per 64-row chunk: scores via bf16 MFMA, chunk softmax stats (m_c, z_c),
// and unnormalized partial context cpart[chunk][d] = sum_row e^{s-m_c} * values[row][d],
// computed from the bf16 LDS copy (single HBM pass over values).
// block = 64 rows of one batch, 256 threads (4 waves); wave w owns cols [64w, 64w+64)
__global__ void kb_scores(const float* __restrict__ values, const ushort* __restrict__ W1p,
                          const float* __restrict__ pqb, const float* __restrict__ V,
                          const float* __restrict__ bV, float* __restrict__ scores,
                          float* __restrict__ cstats, float* __restrict__ cpart) {
    __shared__ ushort Alds[ROWS * 256];  // 64 rows x 256 bf16, XOR-swizzled
    __shared__ float red[4][ROWS];
    __shared__ float wch[ROWS];
    int b = blockIdx.x >> 6;
    int s0 = (blockIdx.x & 63) * ROWS;
    int t = threadIdx.x;
    int w = t >> 6, l = t & 63;
    char* lds = (char*)Alds;

    // stage 64x256 fp32 -> bf16 LDS, swizzled byte ^= (row&7)<<4
    const float* src = values + ((size_t)(b * S + s0)) * D;
#pragma unroll
    for (int i = 0; i < 16; ++i) {
        int row = i * 4 + w;
        int col = l * 4;
        float4 v = *(const float4*)&src[row * 256 + col];
        ushort4 h;
        h.x = f2bf(v.x); h.y = f2bf(v.y); h.z = f2bf(v.z); h.w = f2bf(v.w);
        int byte = (row * 512 + col * 2) ^ ((row & 7) << 4);
        *(ushort4*)(lds + byte) = h;
    }
    __syncthreads();

    int lrow = l & 15, lk = l >> 4;
    f32x4 acc[4][4];
#pragma unroll
    for (int mt = 0; mt < 4; ++mt)
#pragma unroll
        for (int nt = 0; nt < 4; ++nt) acc[mt][nt] = (f32x4){0.f, 0.f, 0.f, 0.f};

    for (int kk = 0; kk < 8; ++kk) {
        short8 afr[4], bfr[4];
#pragma unroll
        for (int mt = 0; mt < 4; ++mt) {
            int row = mt * 16 + lrow;
            int byte = (row * 512 + kk * 64 + lk * 16) ^ ((row & 7) << 4);
            afr[mt] = *(const short8*)(lds + byte);
        }
#pragma unroll
        for (int nt = 0; nt < 4; ++nt) {
            int ntile = w * 4 + nt;
            bfr[nt] = *(const short8*)&W1p[(((ntile * 8) + kk) * 64 + l) * 8];
        }
#pragma unroll
        for (int mt = 0; mt < 4; ++mt)
#pragma unroll
            for (int nt = 0; nt < 4; ++nt)
                acc[mt][nt] = __builtin_amdgcn_mfma_f32_16x16x32_bf16(
                    afr[mt], bfr[nt], acc[mt][nt], 0, 0, 0);
    }

    // epilogue: tanh, .V, reduce over u
    float bb[4], vv[4];
#pragma unroll
    for (int nt = 0; nt < 4; ++nt) {
        int u = (w * 4 + nt) * 16 + lrow;
        bb[nt] = pqb[b * U + u];
        vv[nt] = V[u];
    }
#pragma unroll
    for (int mt = 0; mt < 4; ++mt) {
#pragma unroll
        for (int r = 0; r < 4; ++r) {
            float s = 0.f;
#pragma unroll
            for (int nt = 0; nt < 4; ++nt)
                s += fast_tanh(acc[mt][nt][r] + bb[nt]) * vv[nt];
            s += __shfl_xor(s, 1);
            s += __shfl_xor(s, 2);
            s += __shfl_xor(s, 4);
            s += __shfl_xor(s, 8);
            if (lrow == 0) red[w][mt * 16 + lk * 4 + r] = s;
        }
    }
    __syncthreads();
    if (t < ROWS) {  // wave 0
        float s = red[0][t] + red[1][t] + red[2][t] + red[3][t] + bV[0];
        scores[b * S + s0 + t] = s;
        float m = s;
#pragma unroll
        for (int off = 32; off; off >>= 1) m = fmaxf(m, __shfl_xor(m, off));
        float z0 = __expf(s - m);
        wch[t] = z0;
        float z = z0;
#pragma unroll
        for (int off = 32; off; off >>= 1) z += __shfl_xor(z, off);
        if (t == 0) {
            cstats[2 * blockIdx.x] = m;
            cstats[2 * blockIdx.x + 1] = z;
        }
    }
    __syncthreads();

    // partial context from the bf16 LDS copy: thread t owns column t.
    // ds_read_u16: 64 lanes x 2B contiguous per row = 2 lanes/bank (conflict-free).
    float cacc = 0.f;
#pragma unroll 8
    for (int r = 0; r < ROWS; ++r) {
        int byte = (r * 512 + t * 2) ^ ((r & 7) << 4);
        ushort u = *(const ushort*)(lds + byte);
        cacc = fmaf(wch[r], bf2f(u), cacc);
    }
    cpart[(size_t)blockIdx.x * D + t] = cacc;
}

// KC: finisher. 4 blocks per batch (q = quarter).
//  - reduce 64 chunk stats -> M, Z (redundant per block)
//  - ctx[b][q*64 + dl] = sum_c e^{m_c-M} cpart[c][d] / Z
//  - wout[b][q*1024 .. +1024) = e^{score-M}/Z
__global__ void kc_final(const float* __restrict__ scores, const float* __restrict__ cstats,
                         const float* __restrict__ cpart, float* __restrict__ wout,
                         float* __restrict__ ctx) {
    __shared__ float scl[NCHK];
    __shared__ float stats[2];
    __shared__ float part[4][64];
    int b = blockIdx.x >> 2, q = blockIdx.x & 3;
    int t = threadIdx.x;

    if (t < 64) {
        float m = cstats[2 * (b * NCHK + t)];
        float z = cstats[2 * (b * NCHK + t) + 1];
        float M = m;
#pragma unroll
        for (int off = 32; off; off >>= 1) M = fmaxf(M, __shfl_xor(M, off));
        float zz = z * __expf(m - M);
#pragma unroll
        for (int off = 32; off; off >>= 1) zz += __shfl_xor(zz, off);
        scl[t] = __expf(m - M);
        if (t == 0) { stats[0] = M; stats[1] = zz; }
    }
    __syncthreads();
    float M = stats[0];
    float invZ = 1.0f / stats[1];

    int tq = t >> 6, dl = t & 63;
    int d = q * 64 + dl;
    float acc = 0.f;
#pragma unroll
    for (int i = 0; i < 16; ++i) {
        int c = tq * 16 + i;
        acc = fmaf(scl[c], cpart[(size_t)(b * NCHK + c) * D + d], acc);
    }
    part[tq][dl] = acc;

#pragma unroll
    for (int i = 0; i < 4; ++i) {
        int s = q * 1024 + i * 256 + t;
        wout[b * S + s] = __expf(scores[b * S + s] - M) * invZ;
    }
    __syncthreads();
    if (t < 64)
        ctx[b * D + q * 64 + t] =
            (part[0][t] + part[1][t] + part[2][t] + part[3][t]) * invZ;
}

extern "C" void kernel_launch(void* const* d_in, const int* in_sizes, int n_in,
                              void* d_out, int out_size, void* d_ws, size_t ws_size,
                              hipStream_t stream) {
    const float* values = (const float*)d_in[0];
    const float* query  = (const float*)d_in[1];
    const float* W1     = (const float*)d_in[2];
    const float* b1     = (const float*)d_in[3];
    const float* W2     = (const float*)d_in[4];
    const float* b2     = (const float*)d_in[5];
    const float* V      = (const float*)d_in[6];
    const float* bV     = (const float*)d_in[7];

    float* out  = (float*)d_out;
    float* ctx  = out;          // [B, D]
    float* wout = out + B * D;  // [B, S, 1]

    float* ws     = (float*)d_ws;
    float* pqb    = ws;                 // B*U          = 4096
    float* scores = pqb + B * U;        // B*S          = 65536
    float* cstats = scores + B * S;     // 2*B*NCHK     = 2048
    float* cpart  = cstats + 2048;      // B*NCHK*D     = 262144
    ushort* W1p   = (ushort*)(cpart + B * NCHK * D);  // 65536 ushorts

    ka_setup<<<24, 256, 0, stream>>>(query, W2, b2, b1, W1, pqb, W1p);
    kb_scores<<<B * NCHK, 256, 0, stream>>>(values, W1p, pqb, V, bV, scores, cstats, cpart);
    kc_final<<<B * 4, 256, 0, stream>>>(scores, cstats, cpart, wout, ctx);
}